// Round 1
// baseline (786.488 us; speedup 1.0000x reference)
//
#include <hip/hip_runtime.h>

typedef short v8s __attribute__((ext_vector_type(8)));
typedef float v4f __attribute__((ext_vector_type(4)));

// ---- problem constants ----
#define L_SEQ  2048
#define DPROJ  8352
#define CONVD  4224
#define DIN    4096
#define NH     32
#define HD     128
#define NSTATE 64
#define NCHUNK 8
#define CKLEN  256

__device__ __forceinline__ unsigned short to_bf16(float f) {
  unsigned u = __float_as_uint(f);
  return (unsigned short)((u + 0x7fffu + ((u >> 16) & 1u)) >> 16);
}

// ---------------- fp32 -> bf16 cast ----------------
__global__ void cvt_bf16_kernel(const float* __restrict__ in,
                                unsigned short* __restrict__ out, int n) {
  int i = blockIdx.x * 256 + threadIdx.x;
  if (i < n) out[i] = to_bf16(in[i]);
}

// ---------------- bf16 NT GEMM: C[M,N] = A[M,K] * B[N,K]^T (fp32 out) -----
// 128x128 block tile, BK=32, 4 waves (2x2), each wave 64x64 via 4x4 MFMA tiles.
__global__ __launch_bounds__(256) void gemm_nt_bf16(
    const unsigned short* __restrict__ A, const unsigned short* __restrict__ B,
    float* __restrict__ C, int M, int N, int K)
{
  __shared__ unsigned short As[128 * 32];
  __shared__ unsigned short Bs[128 * 32];
  const int m0 = blockIdx.x * 128;
  const int n0 = blockIdx.y * 128;
  const int tid = threadIdx.x;
  const int wave = tid >> 6, lane = tid & 63;
  const int wm = (wave & 1) * 64, wn = (wave >> 1) * 64;
  const int lrow = lane & 15, lquad = lane >> 4;

  v4f acc[4][4] = {};

  for (int k0 = 0; k0 < K; k0 += 32) {
    __syncthreads();
#pragma unroll
    for (int rep = 0; rep < 2; ++rep) {
      int e = tid + rep * 256;          // 0..511
      int row = e >> 2;                 // 0..127
      int kq = (e & 3) * 8;             // 0,8,16,24
      const unsigned short* ap = A + (size_t)(m0 + row) * K + k0 + kq;
      *(v8s*)&As[row * 32 + kq] = *(const v8s*)ap;
      int br = n0 + row; if (br >= N) br = N - 1;
      const unsigned short* bp = B + (size_t)br * K + k0 + kq;
      *(v8s*)&Bs[row * 32 + kq] = *(const v8s*)bp;
    }
    __syncthreads();
    v8s af[4], bfr[4];
#pragma unroll
    for (int i = 0; i < 4; ++i)
      af[i] = *(const v8s*)&As[(wm + i * 16 + lrow) * 32 + lquad * 8];
#pragma unroll
    for (int j = 0; j < 4; ++j)
      bfr[j] = *(const v8s*)&Bs[(wn + j * 16 + lrow) * 32 + lquad * 8];
#pragma unroll
    for (int i = 0; i < 4; ++i)
#pragma unroll
      for (int j = 0; j < 4; ++j)
        acc[i][j] = __builtin_amdgcn_mfma_f32_16x16x32_bf16(af[i], bfr[j], acc[i][j], 0, 0, 0);
  }

#pragma unroll
  for (int i = 0; i < 4; ++i) {
    int grow = m0 + wm + i * 16 + lquad * 4;
#pragma unroll
    for (int j = 0; j < 4; ++j) {
      int gcol = n0 + wn + j * 16 + lrow;
      if (gcol < N) {
#pragma unroll
        for (int r = 0; r < 4; ++r)
          C[(size_t)(grow + r) * N + gcol] = acc[i][j][r];
      }
    }
  }
}

// ---------------- causal depthwise conv1d(4) + SiLU ----------------
__global__ void conv_silu_kernel(const float* __restrict__ zx,
                                 const float* __restrict__ cw,
                                 const float* __restrict__ cb,
                                 float* __restrict__ out)
{
  int e = blockIdx.x * 256 + threadIdx.x;   // over L_SEQ*CONVD
  int l = e / CONVD, c = e % CONVD;
  float acc = cb[c];
#pragma unroll
  for (int j = 0; j < 4; ++j) {
    int ls = l - 3 + j;
    if (ls >= 0) acc += zx[(size_t)ls * DPROJ + DIN + c] * cw[c * 4 + j];
  }
  out[e] = acc / (1.f + __expf(-acc));
}

// ---------------- dt = softplus(raw + bias) ----------------
__global__ void dt_kernel(const float* __restrict__ zx,
                          const float* __restrict__ dtb,
                          float* __restrict__ dt)
{
  int e = blockIdx.x * 256 + threadIdx.x;   // over L_SEQ*NH
  int l = e >> 5, h = e & 31;
  float v = zx[(size_t)l * DPROJ + (DPROJ - NH) + h] + dtb[h];
  dt[e] = (v > 20.f) ? v : log1pf(__expf(v));
}

// ---------------- per-(head,chunk) inclusive cumsum of A*dt ----------------
__global__ void acum_kernel(const float* __restrict__ dt,
                            const float* __restrict__ alog,
                            float* __restrict__ acum)
{
  int h = blockIdx.x & 31, c = blockIdx.x >> 5;
  int t = threadIdx.x;
  int l = c * CKLEN + t;
  float A = -__expf(alog[h]);
  __shared__ float s[256];
  s[t] = A * dt[l * NH + h];
  __syncthreads();
  for (int off = 1; off < 256; off <<= 1) {
    float add = (t >= off) ? s[t - off] : 0.f;
    __syncthreads();
    s[t] += add;
    __syncthreads();
  }
  acum[h * L_SEQ + l] = s[t];
}

// ---------------- G[c][l][s] = C_l . B_s (per chunk) ----------------
__global__ __launch_bounds__(256) void g_kernel(const float* __restrict__ xbc,
                                                float* __restrict__ G)
{
  int c = blockIdx.z;
  int l0 = blockIdx.y * 64, s0 = blockIdx.x * 64;
  __shared__ float Cs[64][65];
  __shared__ float Bs[64][65];
  int tid = threadIdx.x;
  for (int e = tid; e < 64 * 64; e += 256) {
    int r = e >> 6, k = e & 63;
    Cs[r][k] = xbc[(size_t)(c * CKLEN + l0 + r) * CONVD + DIN + NSTATE + k];
    Bs[r][k] = xbc[(size_t)(c * CKLEN + s0 + r) * CONVD + DIN + k];
  }
  __syncthreads();
  int tx = tid & 15, ty = tid >> 4;
  float acc[4][4] = {};
  for (int k = 0; k < 64; ++k) {
    float a[4], b[4];
#pragma unroll
    for (int i = 0; i < 4; ++i) a[i] = Cs[ty * 4 + i][k];
#pragma unroll
    for (int j = 0; j < 4; ++j) b[j] = Bs[tx * 4 + j][k];
#pragma unroll
    for (int i = 0; i < 4; ++i)
#pragma unroll
      for (int j = 0; j < 4; ++j) acc[i][j] += a[i] * b[j];
  }
  for (int i = 0; i < 4; ++i)
    for (int j = 0; j < 4; ++j)
      G[((size_t)c * CKLEN + l0 + ty * 4 + i) * CKLEN + s0 + tx * 4 + j] = acc[i][j];
}

// ---------------- chunk states: st[c][h][p][n] ----------------
__global__ __launch_bounds__(256) void states_kernel(const float* __restrict__ xbc,
                                                     const float* __restrict__ dt,
                                                     const float* __restrict__ acum,
                                                     float* __restrict__ st)
{
  int h = blockIdx.x & 31, c = blockIdx.x >> 5;
  int tid = threadIdx.x;
  int p = tid >> 1, nh = (tid & 1) * 32;
  __shared__ float Xs[32][128];
  __shared__ float Bs[32][64];
  __shared__ float Ws[32];
  float alast = acum[h * L_SEQ + c * CKLEN + 255];
  float acc[32] = {};
  for (int t0 = 0; t0 < CKLEN; t0 += 32) {
    __syncthreads();
    for (int e = tid; e < 32 * 128; e += 256) {
      int tt = e >> 7, pp = e & 127;
      int l = c * CKLEN + t0 + tt;
      Xs[tt][pp] = xbc[(size_t)l * CONVD + h * HD + pp] * dt[l * NH + h];
    }
    for (int e = tid; e < 32 * 64; e += 256) {
      int tt = e >> 6, nn = e & 63;
      int l = c * CKLEN + t0 + tt;
      Bs[tt][nn] = xbc[(size_t)l * CONVD + DIN + nn];
    }
    if (tid < 32) {
      int l = c * CKLEN + t0 + tid;
      Ws[tid] = __expf(fminf(alast - acum[h * L_SEQ + l], 0.f));
    }
    __syncthreads();
    for (int tt = 0; tt < 32; ++tt) {
      float xw = Xs[tt][p] * Ws[tt];
      const float4* bp = (const float4*)&Bs[tt][nh];
#pragma unroll
      for (int j = 0; j < 8; ++j) {
        float4 b4 = bp[j];
        acc[j * 4 + 0] += xw * b4.x;
        acc[j * 4 + 1] += xw * b4.y;
        acc[j * 4 + 2] += xw * b4.z;
        acc[j * 4 + 3] += xw * b4.w;
      }
    }
  }
  float* outp = st + ((size_t)c * NH + h) * (HD * NSTATE) + p * NSTATE + nh;
#pragma unroll
  for (int j = 0; j < 32; ++j) outp[j] = acc[j];
}

// ---------------- inter-chunk scan: sp[c] = states entering chunk c ---------
__global__ void scan_kernel(const float* __restrict__ acum,
                            const float* __restrict__ st,
                            float* __restrict__ sp)
{
  int e = blockIdx.x * 256 + threadIdx.x;   // over NH*HD*NSTATE = 262144
  int h = e >> 13;
  float running = 0.f;
#pragma unroll
  for (int c = 0; c < NCHUNK; ++c) {
    sp[(size_t)c * 262144 + e] = running;
    float dec = __expf(fminf(acum[h * L_SEQ + c * CKLEN + 255], 0.f));
    running = running * dec + st[(size_t)c * 262144 + e];
  }
}

// ---------------- Y = diag + offdiag(state) + D*xs ----------------
__global__ __launch_bounds__(256) void y_kernel(const float* __restrict__ xbc,
                                                const float* __restrict__ dt,
                                                const float* __restrict__ acum,
                                                const float* __restrict__ G,
                                                const float* __restrict__ sp,
                                                const float* __restrict__ Dp,
                                                float* __restrict__ Y)
{
  const int h = blockIdx.x & 31, c = blockIdx.x >> 5;
  const int t = threadIdx.x;                 // local row l
  const int Lg = c * CKLEN + t;
  const float acum_l = acum[h * L_SEQ + Lg];
  __shared__ float Xs[32][128];
  __shared__ float Ss[32][132];
  __shared__ float As[32];
  float acc[128];
#pragma unroll
  for (int q = 0; q < 128; ++q) acc[q] = 0.f;

  const float* Grow = G + (size_t)c * (CKLEN * CKLEN) + (size_t)t * CKLEN;

  for (int s0 = 0; s0 < CKLEN; s0 += 32) {
    __syncthreads();
    for (int e = t; e < 32 * 128; e += 256) {
      int ssi = e >> 7, pp = e & 127;
      int ls = c * CKLEN + s0 + ssi;
      Xs[ssi][pp] = xbc[(size_t)ls * CONVD + h * HD + pp] * dt[ls * NH + h];
    }
    if (t < 32) As[t] = acum[h * L_SEQ + c * CKLEN + s0 + t];
    __syncthreads();
    if (s0 <= t) {
      for (int ssi = 0; ssi < 32; ++ssi) {
        int s = s0 + ssi;
        float m = (s <= t) ? Grow[s] * __expf(fminf(acum_l - As[ssi], 0.f)) : 0.f;
        const float4* xp = (const float4*)&Xs[ssi][0];
#pragma unroll
        for (int q = 0; q < 32; ++q) {
          float4 x4 = xp[q];
          acc[q * 4 + 0] += m * x4.x;
          acc[q * 4 + 1] += m * x4.y;
          acc[q * 4 + 2] += m * x4.z;
          acc[q * 4 + 3] += m * x4.w;
        }
      }
    }
  }

  // state contribution: acc[p] += exp(acum_l) * sum_n C[l,n] * sp[h][p][n]
  const float eAl = __expf(fminf(acum_l, 0.f));
  const float* Crow = xbc + (size_t)Lg * CONVD + DIN + NSTATE;
  const float* Sph = sp + ((size_t)c * NH + h) * (HD * NSTATE);
  for (int n0 = 0; n0 < NSTATE; n0 += 32) {
    __syncthreads();
    for (int e = t; e < 32 * 128; e += 256) {
      int nn = e & 31, pp = e >> 5;
      Ss[nn][pp] = Sph[(size_t)pp * NSTATE + n0 + nn];
    }
    __syncthreads();
    for (int nn = 0; nn < 32; ++nn) {
      float coeff = Crow[n0 + nn] * eAl;
#pragma unroll
      for (int q = 0; q < 32; ++q) {
        float4 s4 = *(const float4*)&Ss[nn][q * 4];
        acc[q * 4 + 0] += coeff * s4.x;
        acc[q * 4 + 1] += coeff * s4.y;
        acc[q * 4 + 2] += coeff * s4.z;
        acc[q * 4 + 3] += coeff * s4.w;
      }
    }
  }

  const float Dh = Dp[h];
  float* yrow = Y + (size_t)Lg * DIN + h * HD;
  const float* xsrow = xbc + (size_t)Lg * CONVD + h * HD;
#pragma unroll
  for (int q = 0; q < 128; ++q) yrow[q] = acc[q] + Dh * xsrow[q];
}

// ---------------- gated RMSNorm -> bf16 ----------------
__global__ __launch_bounds__(256) void norm_gate_kernel(const float* __restrict__ Y,
                                                        const float* __restrict__ zx,
                                                        const float* __restrict__ nw,
                                                        unsigned short* __restrict__ gbf)
{
  int l = blockIdx.x;
  int t = threadIdx.x;
  float g[16];
  float ss = 0.f;
#pragma unroll
  for (int i = 0; i < 16; ++i) {
    int idx = i * 256 + t;
    float z = zx[(size_t)l * DPROJ + idx];
    float y = Y[(size_t)l * DIN + idx];
    float gv = y * (z / (1.f + __expf(-z)));
    g[i] = gv;
    ss += gv * gv;
  }
#pragma unroll
  for (int off = 32; off > 0; off >>= 1) ss += __shfl_down(ss, off);
  __shared__ float red[4];
  if ((t & 63) == 0) red[t >> 6] = ss;
  __syncthreads();
  float total = red[0] + red[1] + red[2] + red[3];
  float scale = rsqrtf(total / (float)DIN + 1e-5f);
#pragma unroll
  for (int i = 0; i < 16; ++i) {
    int idx = i * 256 + t;
    gbf[(size_t)l * DIN + idx] = to_bf16(g[i] * scale * nw[idx]);
  }
}

// ---------------- launch ----------------
extern "C" void kernel_launch(void* const* d_in, const int* in_sizes, int n_in,
                              void* d_out, int out_size, void* d_ws, size_t ws_size,
                              hipStream_t stream) {
  const float* x    = (const float*)d_in[0];
  const float* w1   = (const float*)d_in[1];
  const float* cw   = (const float*)d_in[2];
  const float* cb   = (const float*)d_in[3];
  const float* dtb  = (const float*)d_in[4];
  const float* alog = (const float*)d_in[5];
  const float* Dp   = (const float*)d_in[6];
  const float* nw   = (const float*)d_in[7];
  const float* w2   = (const float*)d_in[8];
  float* out = (float*)d_out;
  float* ws  = (float*)d_ws;

  // scratch layout (float units, all 64-aligned); total ~58.0M floats (~222 MiB)
  unsigned short* xbf  = (unsigned short*)(ws + 0);          // 2048*2048 bf16
  unsigned short* w1bf = (unsigned short*)(ws + 2097152);    // 8352*2048 bf16
  unsigned short* w2bf = (unsigned short*)(ws + 10649600);   // 2048*4096 bf16
  float* zx   = ws + 14843904;   // 2048*8352
  float* xbc  = ws + 31948800;   // 2048*4224
  float* dt   = ws + 40599552;   // 2048*32
  float* acum = ws + 40665088;   // 32*2048
  float* G    = ws + 40730624;   // 8*256*256
  float* st   = ws + 41254912;   // 8*32*128*64
  float* sp   = ws + 43352064;   // 8*32*128*64
  float* Y    = ws + 45449216;   // 2048*4096
  unsigned short* gbf = (unsigned short*)(ws + 53837824);    // 2048*4096 bf16

  cvt_bf16_kernel<<<(4194304 + 255) / 256, 256, 0, stream>>>(x, xbf, 4194304);
  cvt_bf16_kernel<<<(17104896 + 255) / 256, 256, 0, stream>>>(w1, w1bf, 17104896);
  cvt_bf16_kernel<<<(8388608 + 255) / 256, 256, 0, stream>>>(w2, w2bf, 8388608);

  // zxbcdt = x @ in_proj_w^T   (M=2048, N=8352, K=2048)
  gemm_nt_bf16<<<dim3(16, 66), 256, 0, stream>>>(xbf, w1bf, zx, 2048, 8352, 2048);

  conv_silu_kernel<<<(L_SEQ * CONVD) / 256, 256, 0, stream>>>(zx, cw, cb, xbc);
  dt_kernel<<<(L_SEQ * NH) / 256, 256, 0, stream>>>(zx, dtb, dt);
  acum_kernel<<<NCHUNK * NH, 256, 0, stream>>>(dt, alog, acum);
  g_kernel<<<dim3(4, 4, NCHUNK), 256, 0, stream>>>(xbc, G);
  states_kernel<<<NCHUNK * NH, 256, 0, stream>>>(xbc, dt, acum, st);
  scan_kernel<<<262144 / 256, 256, 0, stream>>>(acum, st, sp);
  y_kernel<<<NCHUNK * NH, 256, 0, stream>>>(xbc, dt, acum, G, sp, Dp, Y);
  norm_gate_kernel<<<L_SEQ, 256, 0, stream>>>(Y, zx, nw, gbf);

  // out = g @ out_proj_w^T   (M=2048, N=2048, K=4096)
  gemm_nt_bf16<<<dim3(16, 16), 256, 0, stream>>>(gbf, w2bf, out, 2048, 2048, 4096);
}

// Round 2
// 629.861 us; speedup vs baseline: 1.2487x; 1.2487x over previous
//
#include <hip/hip_runtime.h>

typedef short v8s __attribute__((ext_vector_type(8)));
typedef float v4f __attribute__((ext_vector_type(4)));

// ---- problem constants ----
#define L_SEQ  2048
#define DPROJ  8352
#define CONVD  4224
#define DIN    4096
#define NH     32
#define HD     128
#define NSTATE 64
#define NCHUNK 8
#define CKLEN  256

__device__ __forceinline__ unsigned short to_bf16(float f) {
  unsigned u = __float_as_uint(f);
  return (unsigned short)((u + 0x7fffu + ((u >> 16) & 1u)) >> 16);
}

// ---------------- fp32 -> bf16 cast ----------------
__global__ void cvt_bf16_kernel(const float* __restrict__ in,
                                unsigned short* __restrict__ out, int n) {
  int i = blockIdx.x * 256 + threadIdx.x;
  if (i < n) out[i] = to_bf16(in[i]);
}

// ---------------- bf16 NT GEMM: C[M,N] = A[M,K] * B[N,K]^T (fp32 out) -----
__global__ __launch_bounds__(256) void gemm_nt_bf16(
    const unsigned short* __restrict__ A, const unsigned short* __restrict__ B,
    float* __restrict__ C, int M, int N, int K)
{
  __shared__ unsigned short As[128 * 32];
  __shared__ unsigned short Bs[128 * 32];
  const int m0 = blockIdx.x * 128;
  const int n0 = blockIdx.y * 128;
  const int tid = threadIdx.x;
  const int wave = tid >> 6, lane = tid & 63;
  const int wm = (wave & 1) * 64, wn = (wave >> 1) * 64;
  const int lrow = lane & 15, lquad = lane >> 4;

  v4f acc[4][4] = {};

  for (int k0 = 0; k0 < K; k0 += 32) {
    __syncthreads();
#pragma unroll
    for (int rep = 0; rep < 2; ++rep) {
      int e = tid + rep * 256;          // 0..511
      int row = e >> 2;                 // 0..127
      int kq = (e & 3) * 8;             // 0,8,16,24
      const unsigned short* ap = A + (size_t)(m0 + row) * K + k0 + kq;
      *(v8s*)&As[row * 32 + kq] = *(const v8s*)ap;
      int br = n0 + row; if (br >= N) br = N - 1;
      const unsigned short* bp = B + (size_t)br * K + k0 + kq;
      *(v8s*)&Bs[row * 32 + kq] = *(const v8s*)bp;
    }
    __syncthreads();
    v8s af[4], bfr[4];
#pragma unroll
    for (int i = 0; i < 4; ++i)
      af[i] = *(const v8s*)&As[(wm + i * 16 + lrow) * 32 + lquad * 8];
#pragma unroll
    for (int j = 0; j < 4; ++j)
      bfr[j] = *(const v8s*)&Bs[(wn + j * 16 + lrow) * 32 + lquad * 8];
#pragma unroll
    for (int i = 0; i < 4; ++i)
#pragma unroll
      for (int j = 0; j < 4; ++j)
        acc[i][j] = __builtin_amdgcn_mfma_f32_16x16x32_bf16(af[i], bfr[j], acc[i][j], 0, 0, 0);
  }

#pragma unroll
  for (int i = 0; i < 4; ++i) {
    int grow = m0 + wm + i * 16 + lquad * 4;
#pragma unroll
    for (int j = 0; j < 4; ++j) {
      int gcol = n0 + wn + j * 16 + lrow;
      if (gcol < N) {
#pragma unroll
        for (int r = 0; r < 4; ++r)
          C[(size_t)(grow + r) * N + gcol] = acc[i][j][r];
      }
    }
  }
}

// ---------------- causal depthwise conv1d(4) + SiLU ----------------
__global__ void conv_silu_kernel(const float* __restrict__ zx,
                                 const float* __restrict__ cw,
                                 const float* __restrict__ cb,
                                 float* __restrict__ out)
{
  int e = blockIdx.x * 256 + threadIdx.x;   // over L_SEQ*CONVD
  int l = e / CONVD, c = e % CONVD;
  float acc = cb[c];
#pragma unroll
  for (int j = 0; j < 4; ++j) {
    int ls = l - 3 + j;
    if (ls >= 0) acc += zx[(size_t)ls * DPROJ + DIN + c] * cw[c * 4 + j];
  }
  out[e] = acc / (1.f + __expf(-acc));
}

// ---------------- dt = softplus(raw + bias) ----------------
__global__ void dt_kernel(const float* __restrict__ zx,
                          const float* __restrict__ dtb,
                          float* __restrict__ dt)
{
  int e = blockIdx.x * 256 + threadIdx.x;   // over L_SEQ*NH
  int l = e >> 5, h = e & 31;
  float v = zx[(size_t)l * DPROJ + (DPROJ - NH) + h] + dtb[h];
  dt[e] = (v > 20.f) ? v : log1pf(__expf(v));
}

// ---------------- per-(head,chunk) inclusive cumsum of A*dt ----------------
__global__ void acum_kernel(const float* __restrict__ dt,
                            const float* __restrict__ alog,
                            float* __restrict__ acum)
{
  int h = blockIdx.x & 31, c = blockIdx.x >> 5;
  int t = threadIdx.x;
  int l = c * CKLEN + t;
  float A = -__expf(alog[h]);
  __shared__ float s[256];
  s[t] = A * dt[l * NH + h];
  __syncthreads();
  for (int off = 1; off < 256; off <<= 1) {
    float add = (t >= off) ? s[t - off] : 0.f;
    __syncthreads();
    s[t] += add;
    __syncthreads();
  }
  acum[h * L_SEQ + l] = s[t];
}

// ---------------- G[c][l][s] = C_l . B_s (per chunk) ----------------
__global__ __launch_bounds__(256) void g_kernel(const float* __restrict__ xbc,
                                                float* __restrict__ G)
{
  int c = blockIdx.z;
  int l0 = blockIdx.y * 64, s0 = blockIdx.x * 64;
  __shared__ float Cs[64][65];
  __shared__ float Bs[64][65];
  int tid = threadIdx.x;
  for (int e = tid; e < 64 * 64; e += 256) {
    int r = e >> 6, k = e & 63;
    Cs[r][k] = xbc[(size_t)(c * CKLEN + l0 + r) * CONVD + DIN + NSTATE + k];
    Bs[r][k] = xbc[(size_t)(c * CKLEN + s0 + r) * CONVD + DIN + k];
  }
  __syncthreads();
  int tx = tid & 15, ty = tid >> 4;
  float acc[4][4] = {};
  for (int k = 0; k < 64; ++k) {
    float a[4], b[4];
#pragma unroll
    for (int i = 0; i < 4; ++i) a[i] = Cs[ty * 4 + i][k];
#pragma unroll
    for (int j = 0; j < 4; ++j) b[j] = Bs[tx * 4 + j][k];
#pragma unroll
    for (int i = 0; i < 4; ++i)
#pragma unroll
      for (int j = 0; j < 4; ++j) acc[i][j] += a[i] * b[j];
  }
  for (int i = 0; i < 4; ++i)
    for (int j = 0; j < 4; ++j)
      G[((size_t)c * CKLEN + l0 + ty * 4 + i) * CKLEN + s0 + tx * 4 + j] = acc[i][j];
}

// ---------------- chunk states: st[c][h][p][n] ----------------
__global__ __launch_bounds__(256) void states_kernel(const float* __restrict__ xbc,
                                                     const float* __restrict__ dt,
                                                     const float* __restrict__ acum,
                                                     float* __restrict__ st)
{
  int h = blockIdx.x & 31, c = blockIdx.x >> 5;
  int tid = threadIdx.x;
  int p = tid >> 1, nh = (tid & 1) * 32;
  __shared__ float Xs[32][128];
  __shared__ float Bs[32][64];
  __shared__ float Ws[32];
  float alast = acum[h * L_SEQ + c * CKLEN + 255];
  float acc[32] = {};
  for (int t0 = 0; t0 < CKLEN; t0 += 32) {
    __syncthreads();
    for (int e = tid; e < 32 * 128; e += 256) {
      int tt = e >> 7, pp = e & 127;
      int l = c * CKLEN + t0 + tt;
      Xs[tt][pp] = xbc[(size_t)l * CONVD + h * HD + pp] * dt[l * NH + h];
    }
    for (int e = tid; e < 32 * 64; e += 256) {
      int tt = e >> 6, nn = e & 63;
      int l = c * CKLEN + t0 + tt;
      Bs[tt][nn] = xbc[(size_t)l * CONVD + DIN + nn];
    }
    if (tid < 32) {
      int l = c * CKLEN + t0 + tid;
      Ws[tid] = __expf(fminf(alast - acum[h * L_SEQ + l], 0.f));
    }
    __syncthreads();
    for (int tt = 0; tt < 32; ++tt) {
      float xw = Xs[tt][p] * Ws[tt];
      const float4* bp = (const float4*)&Bs[tt][nh];
#pragma unroll
      for (int j = 0; j < 8; ++j) {
        float4 b4 = bp[j];
        acc[j * 4 + 0] += xw * b4.x;
        acc[j * 4 + 1] += xw * b4.y;
        acc[j * 4 + 2] += xw * b4.z;
        acc[j * 4 + 3] += xw * b4.w;
      }
    }
  }
  float* outp = st + ((size_t)c * NH + h) * (HD * NSTATE) + p * NSTATE + nh;
#pragma unroll
  for (int j = 0; j < 32; ++j) outp[j] = acc[j];
}

// ---------------- inter-chunk scan: sp[c] = states entering chunk c ---------
__global__ void scan_kernel(const float* __restrict__ acum,
                            const float* __restrict__ st,
                            float* __restrict__ sp)
{
  int e = blockIdx.x * 256 + threadIdx.x;   // over NH*HD*NSTATE = 262144
  int h = e >> 13;
  float running = 0.f;
#pragma unroll
  for (int c = 0; c < NCHUNK; ++c) {
    sp[(size_t)c * 262144 + e] = running;
    float dec = __expf(fminf(acum[h * L_SEQ + c * CKLEN + 255], 0.f));
    running = running * dec + st[(size_t)c * 262144 + e];
  }
}

// ---------------- Y = Mexp @ X + (C*eAl) @ S^T + D*xs  (MFMA bf16) --------
// one block per (chunk, head); Y tile 256x128; K = 256 (diag) + 64 (state)
__global__ __launch_bounds__(256) void y_kernel_mfma(
    const float* __restrict__ xbc, const float* __restrict__ dt,
    const float* __restrict__ acum, const float* __restrict__ G,
    const float* __restrict__ sp, const float* __restrict__ Dp,
    float* __restrict__ Y)
{
  const int h = blockIdx.x & 31, c = blockIdx.x >> 5;
  const int tid = threadIdx.x;
  const int wave = tid >> 6, lane = tid & 63;
  const int wm = wave * 64;           // wave's 64-row band of the 256-row tile
  const int lrow = lane & 15, lquad = lane >> 4;

  __shared__ unsigned short Ms[256 * 32];   // A slab (M rows x BK)
  __shared__ unsigned short Xt[128 * 32];   // B slab transposed (p x BK)
  __shared__ float Ac[256];

  for (int e = tid; e < 256; e += 256)
    Ac[e] = acum[h * L_SEQ + c * CKLEN + e];

  v4f acc[4][8] = {};

  const float* Gc = G + (size_t)c * (CKLEN * CKLEN);

  // ---- diagonal (intra-chunk) part: K = 256 over s ----
  for (int k0 = 0; k0 < CKLEN; k0 += 32) {
    __syncthreads();
    // stage Mexp slab: l in [0,256), s in [k0, k0+32)
#pragma unroll
    for (int i = 0; i < 32; ++i) {
      int e = i * 256 + tid;
      int l = e >> 5, sl = e & 31;
      int s = k0 + sl;
      float m = 0.f;
      if (s <= l) m = Gc[l * CKLEN + s] * __expf(fminf(Ac[l] - Ac[s], 0.f));
      Ms[e] = to_bf16(m);
    }
    // stage X^T slab: Xt[p][ss] = xs[k0+ss][p] * dt
#pragma unroll
    for (int i = 0; i < 16; ++i) {
      int e = i * 256 + tid;
      int ss = e >> 7, p = e & 127;
      int lsg = c * CKLEN + k0 + ss;
      float xv = xbc[(size_t)lsg * CONVD + h * HD + p] * dt[lsg * NH + h];
      Xt[p * 32 + ss] = to_bf16(xv);
    }
    __syncthreads();
    if (k0 < wm + 64) {   // causal skip: this wave's rows are all < k0 otherwise
      v8s af[4], bfr[8];
#pragma unroll
      for (int i = 0; i < 4; ++i)
        af[i] = *(const v8s*)&Ms[(wm + i * 16 + lrow) * 32 + lquad * 8];
#pragma unroll
      for (int j = 0; j < 8; ++j)
        bfr[j] = *(const v8s*)&Xt[(j * 16 + lrow) * 32 + lquad * 8];
#pragma unroll
      for (int i = 0; i < 4; ++i)
#pragma unroll
        for (int j = 0; j < 8; ++j)
          acc[i][j] = __builtin_amdgcn_mfma_f32_16x16x32_bf16(af[i], bfr[j], acc[i][j], 0, 0, 0);
    }
  }

  // ---- state (inter-chunk) part: K = 64 over n ----
  const float* Sph = sp + ((size_t)c * NH + h) * (HD * NSTATE);
  for (int n0 = 0; n0 < NSTATE; n0 += 32) {
    __syncthreads();
#pragma unroll
    for (int i = 0; i < 32; ++i) {
      int e = i * 256 + tid;
      int l = e >> 5, nn = e & 31;
      float cv = xbc[(size_t)(c * CKLEN + l) * CONVD + DIN + NSTATE + n0 + nn]
               * __expf(fminf(Ac[l], 0.f));
      Ms[e] = to_bf16(cv);
    }
#pragma unroll
    for (int i = 0; i < 16; ++i) {
      int e = i * 256 + tid;
      int p = e >> 5, nn = e & 31;
      Xt[p * 32 + nn] = to_bf16(Sph[(size_t)p * NSTATE + n0 + nn]);
    }
    __syncthreads();
    v8s af[4], bfr[8];
#pragma unroll
    for (int i = 0; i < 4; ++i)
      af[i] = *(const v8s*)&Ms[(wm + i * 16 + lrow) * 32 + lquad * 8];
#pragma unroll
    for (int j = 0; j < 8; ++j)
      bfr[j] = *(const v8s*)&Xt[(j * 16 + lrow) * 32 + lquad * 8];
#pragma unroll
    for (int i = 0; i < 4; ++i)
#pragma unroll
      for (int j = 0; j < 8; ++j)
        acc[i][j] = __builtin_amdgcn_mfma_f32_16x16x32_bf16(af[i], bfr[j], acc[i][j], 0, 0, 0);
  }

  // ---- epilogue: + D * xs, write Y ----
  const float Dh = Dp[h];
#pragma unroll
  for (int i = 0; i < 4; ++i) {
    int rbase = wm + i * 16 + lquad * 4;
#pragma unroll
    for (int j = 0; j < 8; ++j) {
      int p = j * 16 + lrow;
#pragma unroll
      for (int r = 0; r < 4; ++r) {
        int Lg = c * CKLEN + rbase + r;
        float xs = xbc[(size_t)Lg * CONVD + h * HD + p];
        Y[(size_t)Lg * DIN + h * HD + p] = acc[i][j][r] + Dh * xs;
      }
    }
  }
}

// ---------------- gated RMSNorm -> bf16 ----------------
__global__ __launch_bounds__(256) void norm_gate_kernel(const float* __restrict__ Y,
                                                        const float* __restrict__ zx,
                                                        const float* __restrict__ nw,
                                                        unsigned short* __restrict__ gbf)
{
  int l = blockIdx.x;
  int t = threadIdx.x;
  float g[16];
  float ss = 0.f;
#pragma unroll
  for (int i = 0; i < 16; ++i) {
    int idx = i * 256 + t;
    float z = zx[(size_t)l * DPROJ + idx];
    float y = Y[(size_t)l * DIN + idx];
    float gv = y * (z / (1.f + __expf(-z)));
    g[i] = gv;
    ss += gv * gv;
  }
#pragma unroll
  for (int off = 32; off > 0; off >>= 1) ss += __shfl_down(ss, off);
  __shared__ float red[4];
  if ((t & 63) == 0) red[t >> 6] = ss;
  __syncthreads();
  float total = red[0] + red[1] + red[2] + red[3];
  float scale = rsqrtf(total / (float)DIN + 1e-5f);
#pragma unroll
  for (int i = 0; i < 16; ++i) {
    int idx = i * 256 + t;
    gbf[(size_t)l * DIN + idx] = to_bf16(g[i] * scale * nw[idx]);
  }
}

// ---------------- launch ----------------
extern "C" void kernel_launch(void* const* d_in, const int* in_sizes, int n_in,
                              void* d_out, int out_size, void* d_ws, size_t ws_size,
                              hipStream_t stream) {
  const float* x    = (const float*)d_in[0];
  const float* w1   = (const float*)d_in[1];
  const float* cw   = (const float*)d_in[2];
  const float* cb   = (const float*)d_in[3];
  const float* dtb  = (const float*)d_in[4];
  const float* alog = (const float*)d_in[5];
  const float* Dp   = (const float*)d_in[6];
  const float* nw   = (const float*)d_in[7];
  const float* w2   = (const float*)d_in[8];
  float* out = (float*)d_out;
  float* ws  = (float*)d_ws;

  // scratch layout (float units)
  unsigned short* xbf  = (unsigned short*)(ws + 0);          // 2048*2048 bf16
  unsigned short* w1bf = (unsigned short*)(ws + 2097152);    // 8352*2048 bf16
  unsigned short* w2bf = (unsigned short*)(ws + 10649600);   // 2048*4096 bf16
  float* zx   = ws + 14843904;   // 2048*8352
  float* xbc  = ws + 31948800;   // 2048*4224
  float* dt   = ws + 40599552;   // 2048*32
  float* acum = ws + 40665088;   // 32*2048
  float* G    = ws + 40730624;   // 8*256*256
  float* st   = ws + 41254912;   // 8*32*128*64
  float* sp   = ws + 43352064;   // 8*32*128*64
  float* Y    = ws + 45449216;   // 2048*4096
  unsigned short* gbf = (unsigned short*)(ws + 53837824);    // 2048*4096 bf16

  cvt_bf16_kernel<<<(4194304 + 255) / 256, 256, 0, stream>>>(x, xbf, 4194304);
  cvt_bf16_kernel<<<(17104896 + 255) / 256, 256, 0, stream>>>(w1, w1bf, 17104896);
  cvt_bf16_kernel<<<(8388608 + 255) / 256, 256, 0, stream>>>(w2, w2bf, 8388608);

  // zxbcdt = x @ in_proj_w^T   (M=2048, N=8352, K=2048)
  gemm_nt_bf16<<<dim3(16, 66), 256, 0, stream>>>(xbf, w1bf, zx, 2048, 8352, 2048);

  conv_silu_kernel<<<(L_SEQ * CONVD) / 256, 256, 0, stream>>>(zx, cw, cb, xbc);
  dt_kernel<<<(L_SEQ * NH) / 256, 256, 0, stream>>>(zx, dtb, dt);
  acum_kernel<<<NCHUNK * NH, 256, 0, stream>>>(dt, alog, acum);
  g_kernel<<<dim3(4, 4, NCHUNK), 256, 0, stream>>>(xbc, G);
  states_kernel<<<NCHUNK * NH, 256, 0, stream>>>(xbc, dt, acum, st);
  scan_kernel<<<262144 / 256, 256, 0, stream>>>(acum, st, sp);
  y_kernel_mfma<<<NCHUNK * NH, 256, 0, stream>>>(xbc, dt, acum, G, sp, Dp, Y);
  norm_gate_kernel<<<L_SEQ, 256, 0, stream>>>(Y, zx, nw, gbf);

  // out = g @ out_proj_w^T   (M=2048, N=2048, K=4096)
  gemm_nt_bf16<<<dim3(16, 16), 256, 0, stream>>>(gbf, w2bf, out, 2048, 2048, 4096);
}

// Round 3
// 617.692 us; speedup vs baseline: 1.2733x; 1.0197x over previous
//
#include <hip/hip_runtime.h>

typedef short v8s __attribute__((ext_vector_type(8)));
typedef float v4f __attribute__((ext_vector_type(4)));

// ---- problem constants ----
#define L_SEQ  2048
#define DPROJ  8352
#define CONVD  4224
#define DIN    4096
#define NH     32
#define HD     128
#define NSTATE 64
#define NCHUNK 8
#define CKLEN  256

#define GLOAD_LDS16(gp, lp) \
  __builtin_amdgcn_global_load_lds((const __attribute__((address_space(1))) void*)(gp), \
                                   (__attribute__((address_space(3))) void*)(lp), 16, 0, 0)

__device__ __forceinline__ unsigned short to_bf16(float f) {
  unsigned u = __float_as_uint(f);
  return (unsigned short)((u + 0x7fffu + ((u >> 16) & 1u)) >> 16);
}

// ---------------- fp32 -> bf16 cast ----------------
__global__ void cvt_bf16_kernel(const float* __restrict__ in,
                                unsigned short* __restrict__ out, int n) {
  int i = blockIdx.x * 256 + threadIdx.x;
  if (i < n) out[i] = to_bf16(in[i]);
}

// ---------------- bf16 NT GEMM: C[M,N] = A[M,K] * B[N,K]^T (fp32 out) -----
// 128x128 tile, BK=32, global_load_lds width=16 staging (m97 pattern).
__global__ __launch_bounds__(256) void gemm_nt_bf16(
    const unsigned short* __restrict__ A, const unsigned short* __restrict__ B,
    float* __restrict__ C, int M, int N, int K)
{
  __shared__ unsigned short As[128 * 32];
  __shared__ unsigned short Bs[128 * 32];
  const int m0 = blockIdx.x * 128;
  const int n0 = blockIdx.y * 128;
  const int tid = threadIdx.x;
  const int wave = tid >> 6, lane = tid & 63;
  const int wm = (wave & 1) * 64, wn = (wave >> 1) * 64;
  const int lrow = lane & 15, lquad = lane >> 4;

  v4f acc[4][4] = {};

  for (int k0 = 0; k0 < K; k0 += 32) {
    __syncthreads();
    // async staging: each wave issues 2 LDS-direct 16B loads for As + 2 for Bs.
    // LDS dest is wave-uniform base + lane*16; our layout is contiguous in e.
#pragma unroll
    for (int r = 0; r < 2; ++r) {
      int e = wave * 128 + r * 64 + lane;   // 0..511
      int row = e >> 2;                     // 0..127
      int kq = (e & 3) * 8;                 // 0,8,16,24
      const unsigned short* ap = A + (size_t)(m0 + row) * K + k0 + kq;
      GLOAD_LDS16(ap, As + wave * 1024 + r * 512);
      int br = n0 + row; if (br >= N) br = N - 1;
      const unsigned short* bp = B + (size_t)br * K + k0 + kq;
      GLOAD_LDS16(bp, Bs + wave * 1024 + r * 512);
    }
    __syncthreads();
    v8s af[4], bfr[4];
#pragma unroll
    for (int i = 0; i < 4; ++i)
      af[i] = *(const v8s*)&As[(wm + i * 16 + lrow) * 32 + lquad * 8];
#pragma unroll
    for (int j = 0; j < 4; ++j)
      bfr[j] = *(const v8s*)&Bs[(wn + j * 16 + lrow) * 32 + lquad * 8];
#pragma unroll
    for (int i = 0; i < 4; ++i)
#pragma unroll
      for (int j = 0; j < 4; ++j)
        acc[i][j] = __builtin_amdgcn_mfma_f32_16x16x32_bf16(af[i], bfr[j], acc[i][j], 0, 0, 0);
  }

#pragma unroll
  for (int i = 0; i < 4; ++i) {
    int grow = m0 + wm + i * 16 + lquad * 4;
#pragma unroll
    for (int j = 0; j < 4; ++j) {
      int gcol = n0 + wn + j * 16 + lrow;
      if (gcol < N) {
#pragma unroll
        for (int r = 0; r < 4; ++r)
          C[(size_t)(grow + r) * N + gcol] = acc[i][j][r];
      }
    }
  }
}

// ---------------- causal depthwise conv1d(4) + SiLU ----------------
__global__ void conv_silu_kernel(const float* __restrict__ zx,
                                 const float* __restrict__ cw,
                                 const float* __restrict__ cb,
                                 float* __restrict__ out)
{
  int e = blockIdx.x * 256 + threadIdx.x;   // over L_SEQ*CONVD
  int l = e / CONVD, c = e % CONVD;
  float acc = cb[c];
#pragma unroll
  for (int j = 0; j < 4; ++j) {
    int ls = l - 3 + j;
    if (ls >= 0) acc += zx[(size_t)ls * DPROJ + DIN + c] * cw[c * 4 + j];
  }
  out[e] = acc / (1.f + __expf(-acc));
}

// ---------------- dt = softplus(raw + bias) ----------------
__global__ void dt_kernel(const float* __restrict__ zx,
                          const float* __restrict__ dtb,
                          float* __restrict__ dt)
{
  int e = blockIdx.x * 256 + threadIdx.x;   // over L_SEQ*NH
  int l = e >> 5, h = e & 31;
  float v = zx[(size_t)l * DPROJ + (DPROJ - NH) + h] + dtb[h];
  dt[e] = (v > 20.f) ? v : log1pf(__expf(v));
}

// ---------------- per-(head,chunk) inclusive cumsum of A*dt ----------------
__global__ void acum_kernel(const float* __restrict__ dt,
                            const float* __restrict__ alog,
                            float* __restrict__ acum)
{
  int h = blockIdx.x & 31, c = blockIdx.x >> 5;
  int t = threadIdx.x;
  int l = c * CKLEN + t;
  float A = -__expf(alog[h]);
  __shared__ float s[256];
  s[t] = A * dt[l * NH + h];
  __syncthreads();
  for (int off = 1; off < 256; off <<= 1) {
    float add = (t >= off) ? s[t - off] : 0.f;
    __syncthreads();
    s[t] += add;
    __syncthreads();
  }
  acum[h * L_SEQ + l] = s[t];
}

// ---------------- G[c][l][s] = C_l . B_s (per chunk) ----------------
__global__ __launch_bounds__(256) void g_kernel(const float* __restrict__ xbc,
                                                float* __restrict__ G)
{
  int c = blockIdx.z;
  int l0 = blockIdx.y * 64, s0 = blockIdx.x * 64;
  __shared__ float Cs[64][65];
  __shared__ float Bs[64][65];
  int tid = threadIdx.x;
  for (int e = tid; e < 64 * 64; e += 256) {
    int r = e >> 6, k = e & 63;
    Cs[r][k] = xbc[(size_t)(c * CKLEN + l0 + r) * CONVD + DIN + NSTATE + k];
    Bs[r][k] = xbc[(size_t)(c * CKLEN + s0 + r) * CONVD + DIN + k];
  }
  __syncthreads();
  int tx = tid & 15, ty = tid >> 4;
  float acc[4][4] = {};
  for (int k = 0; k < 64; ++k) {
    float a[4], b[4];
#pragma unroll
    for (int i = 0; i < 4; ++i) a[i] = Cs[ty * 4 + i][k];
#pragma unroll
    for (int j = 0; j < 4; ++j) b[j] = Bs[tx * 4 + j][k];
#pragma unroll
    for (int i = 0; i < 4; ++i)
#pragma unroll
      for (int j = 0; j < 4; ++j) acc[i][j] += a[i] * b[j];
  }
  for (int i = 0; i < 4; ++i)
    for (int j = 0; j < 4; ++j)
      G[((size_t)c * CKLEN + l0 + ty * 4 + i) * CKLEN + s0 + tx * 4 + j] = acc[i][j];
}

// ---------------- chunk states: st[c][h][p][n] ----------------
__global__ __launch_bounds__(256) void states_kernel(const float* __restrict__ xbc,
                                                     const float* __restrict__ dt,
                                                     const float* __restrict__ acum,
                                                     float* __restrict__ st)
{
  int h = blockIdx.x & 31, c = blockIdx.x >> 5;
  int tid = threadIdx.x;
  int p = tid >> 1, nh = (tid & 1) * 32;
  __shared__ float Xs[32][128];
  __shared__ float Bs[32][64];
  __shared__ float Ws[32];
  float alast = acum[h * L_SEQ + c * CKLEN + 255];
  float acc[32] = {};
  for (int t0 = 0; t0 < CKLEN; t0 += 32) {
    __syncthreads();
    for (int e = tid; e < 32 * 128; e += 256) {
      int tt = e >> 7, pp = e & 127;
      int l = c * CKLEN + t0 + tt;
      Xs[tt][pp] = xbc[(size_t)l * CONVD + h * HD + pp] * dt[l * NH + h];
    }
    for (int e = tid; e < 32 * 64; e += 256) {
      int tt = e >> 6, nn = e & 63;
      int l = c * CKLEN + t0 + tt;
      Bs[tt][nn] = xbc[(size_t)l * CONVD + DIN + nn];
    }
    if (tid < 32) {
      int l = c * CKLEN + t0 + tid;
      Ws[tid] = __expf(fminf(alast - acum[h * L_SEQ + l], 0.f));
    }
    __syncthreads();
    for (int tt = 0; tt < 32; ++tt) {
      float xw = Xs[tt][p] * Ws[tt];
      const float4* bp = (const float4*)&Bs[tt][nh];
#pragma unroll
      for (int j = 0; j < 8; ++j) {
        float4 b4 = bp[j];
        acc[j * 4 + 0] += xw * b4.x;
        acc[j * 4 + 1] += xw * b4.y;
        acc[j * 4 + 2] += xw * b4.z;
        acc[j * 4 + 3] += xw * b4.w;
      }
    }
  }
  float* outp = st + ((size_t)c * NH + h) * (HD * NSTATE) + p * NSTATE + nh;
#pragma unroll
  for (int j = 0; j < 32; ++j) outp[j] = acc[j];
}

// ---------------- inter-chunk scan: sp[c] = states entering chunk c ---------
__global__ void scan_kernel(const float* __restrict__ acum,
                            const float* __restrict__ st,
                            float* __restrict__ sp)
{
  int e = blockIdx.x * 256 + threadIdx.x;   // over NH*HD*NSTATE = 262144
  int h = e >> 13;
  float running = 0.f;
#pragma unroll
  for (int c = 0; c < NCHUNK; ++c) {
    sp[(size_t)c * 262144 + e] = running;
    float dec = __expf(fminf(acum[h * L_SEQ + c * CKLEN + 255], 0.f));
    running = running * dec + st[(size_t)c * 262144 + e];
  }
}

// ---------------- Y = Mexp @ X + (C*eAl) @ S^T + D*xs  (MFMA bf16) --------
__global__ __launch_bounds__(256) void y_kernel_mfma(
    const float* __restrict__ xbc, const float* __restrict__ dt,
    const float* __restrict__ acum, const float* __restrict__ G,
    const float* __restrict__ sp, const float* __restrict__ Dp,
    float* __restrict__ Y)
{
  const int h = blockIdx.x & 31, c = blockIdx.x >> 5;
  const int tid = threadIdx.x;
  const int wave = tid >> 6, lane = tid & 63;
  const int wm = wave * 64;           // wave's 64-row band of the 256-row tile
  const int lrow = lane & 15, lquad = lane >> 4;

  __shared__ unsigned short Ms[256 * 32];   // A slab (M rows x BK)
  __shared__ unsigned short Xt[128 * 32];   // B slab transposed (p x BK)
  __shared__ float Ac[256];

  for (int e = tid; e < 256; e += 256)
    Ac[e] = acum[h * L_SEQ + c * CKLEN + e];

  v4f acc[4][8] = {};

  const float* Gc = G + (size_t)c * (CKLEN * CKLEN);

  // ---- diagonal (intra-chunk) part: K = 256 over s ----
  for (int k0 = 0; k0 < CKLEN; k0 += 32) {
    __syncthreads();
#pragma unroll
    for (int i = 0; i < 32; ++i) {
      int e = i * 256 + tid;
      int l = e >> 5, sl = e & 31;
      int s = k0 + sl;
      float m = 0.f;
      if (s <= l) m = Gc[l * CKLEN + s] * __expf(fminf(Ac[l] - Ac[s], 0.f));
      Ms[e] = to_bf16(m);
    }
#pragma unroll
    for (int i = 0; i < 16; ++i) {
      int e = i * 256 + tid;
      int ss = e >> 7, p = e & 127;
      int lsg = c * CKLEN + k0 + ss;
      float xv = xbc[(size_t)lsg * CONVD + h * HD + p] * dt[lsg * NH + h];
      Xt[p * 32 + ss] = to_bf16(xv);
    }
    __syncthreads();
    if (k0 < wm + 64) {   // causal skip
      v8s af[4], bfr[8];
#pragma unroll
      for (int i = 0; i < 4; ++i)
        af[i] = *(const v8s*)&Ms[(wm + i * 16 + lrow) * 32 + lquad * 8];
#pragma unroll
      for (int j = 0; j < 8; ++j)
        bfr[j] = *(const v8s*)&Xt[(j * 16 + lrow) * 32 + lquad * 8];
#pragma unroll
      for (int i = 0; i < 4; ++i)
#pragma unroll
        for (int j = 0; j < 8; ++j)
          acc[i][j] = __builtin_amdgcn_mfma_f32_16x16x32_bf16(af[i], bfr[j], acc[i][j], 0, 0, 0);
    }
  }

  // ---- state (inter-chunk) part: K = 64 over n ----
  const float* Sph = sp + ((size_t)c * NH + h) * (HD * NSTATE);
  for (int n0 = 0; n0 < NSTATE; n0 += 32) {
    __syncthreads();
#pragma unroll
    for (int i = 0; i < 32; ++i) {
      int e = i * 256 + tid;
      int l = e >> 5, nn = e & 31;
      float cv = xbc[(size_t)(c * CKLEN + l) * CONVD + DIN + NSTATE + n0 + nn]
               * __expf(fminf(Ac[l], 0.f));
      Ms[e] = to_bf16(cv);
    }
#pragma unroll
    for (int i = 0; i < 16; ++i) {
      int e = i * 256 + tid;
      int p = e >> 5, nn = e & 31;
      Xt[p * 32 + nn] = to_bf16(Sph[(size_t)p * NSTATE + n0 + nn]);
    }
    __syncthreads();
    v8s af[4], bfr[8];
#pragma unroll
    for (int i = 0; i < 4; ++i)
      af[i] = *(const v8s*)&Ms[(wm + i * 16 + lrow) * 32 + lquad * 8];
#pragma unroll
    for (int j = 0; j < 8; ++j)
      bfr[j] = *(const v8s*)&Xt[(j * 16 + lrow) * 32 + lquad * 8];
#pragma unroll
    for (int i = 0; i < 4; ++i)
#pragma unroll
      for (int j = 0; j < 8; ++j)
        acc[i][j] = __builtin_amdgcn_mfma_f32_16x16x32_bf16(af[i], bfr[j], acc[i][j], 0, 0, 0);
  }

  // ---- epilogue: + D * xs, write Y ----
  const float Dh = Dp[h];
#pragma unroll
  for (int i = 0; i < 4; ++i) {
    int rbase = wm + i * 16 + lquad * 4;
#pragma unroll
    for (int j = 0; j < 8; ++j) {
      int p = j * 16 + lrow;
#pragma unroll
      for (int r = 0; r < 4; ++r) {
        int Lg = c * CKLEN + rbase + r;
        float xs = xbc[(size_t)Lg * CONVD + h * HD + p];
        Y[(size_t)Lg * DIN + h * HD + p] = acc[i][j][r] + Dh * xs;
      }
    }
  }
}

// ---------------- gated RMSNorm -> bf16 ----------------
__global__ __launch_bounds__(256) void norm_gate_kernel(const float* __restrict__ Y,
                                                        const float* __restrict__ zx,
                                                        const float* __restrict__ nw,
                                                        unsigned short* __restrict__ gbf)
{
  int l = blockIdx.x;
  int t = threadIdx.x;
  float g[16];
  float ss = 0.f;
#pragma unroll
  for (int i = 0; i < 16; ++i) {
    int idx = i * 256 + t;
    float z = zx[(size_t)l * DPROJ + idx];
    float y = Y[(size_t)l * DIN + idx];
    float gv = y * (z / (1.f + __expf(-z)));
    g[i] = gv;
    ss += gv * gv;
  }
#pragma unroll
  for (int off = 32; off > 0; off >>= 1) ss += __shfl_down(ss, off);
  __shared__ float red[4];
  if ((t & 63) == 0) red[t >> 6] = ss;
  __syncthreads();
  float total = red[0] + red[1] + red[2] + red[3];
  float scale = rsqrtf(total / (float)DIN + 1e-5f);
#pragma unroll
  for (int i = 0; i < 16; ++i) {
    int idx = i * 256 + t;
    gbf[(size_t)l * DIN + idx] = to_bf16(g[i] * scale * nw[idx]);
  }
}

// ---------------- launch ----------------
extern "C" void kernel_launch(void* const* d_in, const int* in_sizes, int n_in,
                              void* d_out, int out_size, void* d_ws, size_t ws_size,
                              hipStream_t stream) {
  const float* x    = (const float*)d_in[0];
  const float* w1   = (const float*)d_in[1];
  const float* cw   = (const float*)d_in[2];
  const float* cb   = (const float*)d_in[3];
  const float* dtb  = (const float*)d_in[4];
  const float* alog = (const float*)d_in[5];
  const float* Dp   = (const float*)d_in[6];
  const float* nw   = (const float*)d_in[7];
  const float* w2   = (const float*)d_in[8];
  float* out = (float*)d_out;
  float* ws  = (float*)d_ws;

  // scratch layout (float units)
  unsigned short* xbf  = (unsigned short*)(ws + 0);          // 2048*2048 bf16
  unsigned short* w1bf = (unsigned short*)(ws + 2097152);    // 8352*2048 bf16
  unsigned short* w2bf = (unsigned short*)(ws + 10649600);   // 2048*4096 bf16
  float* zx   = ws + 14843904;   // 2048*8352
  float* xbc  = ws + 31948800;   // 2048*4224
  float* dt   = ws + 40599552;   // 2048*32
  float* acum = ws + 40665088;   // 32*2048
  float* G    = ws + 40730624;   // 8*256*256
  float* st   = ws + 41254912;   // 8*32*128*64
  float* sp   = ws + 43352064;   // 8*32*128*64
  float* Y    = ws + 45449216;   // 2048*4096
  unsigned short* gbf = (unsigned short*)(ws + 53837824);    // 2048*4096 bf16

  cvt_bf16_kernel<<<(4194304 + 255) / 256, 256, 0, stream>>>(x, xbf, 4194304);
  cvt_bf16_kernel<<<(17104896 + 255) / 256, 256, 0, stream>>>(w1, w1bf, 17104896);
  cvt_bf16_kernel<<<(8388608 + 255) / 256, 256, 0, stream>>>(w2, w2bf, 8388608);

  // zxbcdt = x @ in_proj_w^T   (M=2048, N=8352, K=2048)
  gemm_nt_bf16<<<dim3(16, 66), 256, 0, stream>>>(xbf, w1bf, zx, 2048, 8352, 2048);

  conv_silu_kernel<<<(L_SEQ * CONVD) / 256, 256, 0, stream>>>(zx, cw, cb, xbc);
  dt_kernel<<<(L_SEQ * NH) / 256, 256, 0, stream>>>(zx, dtb, dt);
  acum_kernel<<<NCHUNK * NH, 256, 0, stream>>>(dt, alog, acum);
  g_kernel<<<dim3(4, 4, NCHUNK), 256, 0, stream>>>(xbc, G);
  states_kernel<<<NCHUNK * NH, 256, 0, stream>>>(xbc, dt, acum, st);
  scan_kernel<<<262144 / 256, 256, 0, stream>>>(acum, st, sp);
  y_kernel_mfma<<<NCHUNK * NH, 256, 0, stream>>>(xbc, dt, acum, G, sp, Dp, Y);
  norm_gate_kernel<<<L_SEQ, 256, 0, stream>>>(Y, zx, nw, gbf);

  // out = g @ out_proj_w^T   (M=2048, N=2048, K=4096)
  gemm_nt_bf16<<<dim3(16, 16), 256, 0, stream>>>(gbf, w2bf, out, 2048, 2048, 4096);
}

// Round 5
// 521.262 us; speedup vs baseline: 1.5088x; 1.1850x over previous
//
#include <hip/hip_runtime.h>

typedef short v8s __attribute__((ext_vector_type(8)));
typedef float v4f __attribute__((ext_vector_type(4)));

// ---- problem constants ----
#define L_SEQ  2048
#define DPROJ  8352
#define CONVD  4224
#define DIN    4096
#define NH     32
#define HD     128
#define NSTATE 64
#define NCHUNK 8
#define CKLEN  256

#define GLOAD_LDS16(gp, lp) \
  __builtin_amdgcn_global_load_lds((const __attribute__((address_space(1))) void*)(gp), \
                                   (__attribute__((address_space(3))) void*)(lp), 16, 0, 0)

__device__ __forceinline__ unsigned short to_bf16(float f) {
  unsigned u = __float_as_uint(f);
  return (unsigned short)((u + 0x7fffu + ((u >> 16) & 1u)) >> 16);
}

// ---------------- fp32 -> bf16 cast, 8 elts/thread ----------------
__global__ void cvt_bf16_kernel(const float* __restrict__ in,
                                unsigned short* __restrict__ out, int n) {
  int i = (blockIdx.x * 256 + threadIdx.x) * 8;
  if (i + 8 <= n) {
    float4 a = *(const float4*)(in + i);
    float4 b = *(const float4*)(in + i + 4);
    v8s r;
    r[0] = (short)to_bf16(a.x); r[1] = (short)to_bf16(a.y);
    r[2] = (short)to_bf16(a.z); r[3] = (short)to_bf16(a.w);
    r[4] = (short)to_bf16(b.x); r[5] = (short)to_bf16(b.y);
    r[6] = (short)to_bf16(b.z); r[7] = (short)to_bf16(b.w);
    *(v8s*)(out + i) = r;
  }
}

// ---------------- bf16 NT GEMM 128x128: C[M,N] = A[M,K] * B[N,K]^T --------
__global__ __launch_bounds__(256) void gemm_nt_bf16(
    const unsigned short* __restrict__ A, const unsigned short* __restrict__ B,
    float* __restrict__ C, int M, int N, int K)
{
  __shared__ unsigned short As[128 * 32];
  __shared__ unsigned short Bs[128 * 32];
  const int m0 = blockIdx.x * 128;
  const int n0 = blockIdx.y * 128;
  const int tid = threadIdx.x;
  const int wave = tid >> 6, lane = tid & 63;
  const int wm = (wave & 1) * 64, wn = (wave >> 1) * 64;
  const int lrow = lane & 15, lquad = lane >> 4;

  v4f acc[4][4] = {};

  for (int k0 = 0; k0 < K; k0 += 32) {
    __syncthreads();
#pragma unroll
    for (int r = 0; r < 2; ++r) {
      int e = wave * 128 + r * 64 + lane;   // 0..511
      int row = e >> 2;                     // 0..127
      int kq = (e & 3) * 8;                 // 0,8,16,24
      const unsigned short* ap = A + (size_t)(m0 + row) * K + k0 + kq;
      GLOAD_LDS16(ap, As + wave * 1024 + r * 512);
      int br = n0 + row; if (br >= N) br = N - 1;
      const unsigned short* bp = B + (size_t)br * K + k0 + kq;
      GLOAD_LDS16(bp, Bs + wave * 1024 + r * 512);
    }
    __syncthreads();
    v8s af[4], bfr[4];
#pragma unroll
    for (int i = 0; i < 4; ++i)
      af[i] = *(const v8s*)&As[(wm + i * 16 + lrow) * 32 + lquad * 8];
#pragma unroll
    for (int j = 0; j < 4; ++j)
      bfr[j] = *(const v8s*)&Bs[(wn + j * 16 + lrow) * 32 + lquad * 8];
#pragma unroll
    for (int i = 0; i < 4; ++i)
#pragma unroll
      for (int j = 0; j < 4; ++j)
        acc[i][j] = __builtin_amdgcn_mfma_f32_16x16x32_bf16(af[i], bfr[j], acc[i][j], 0, 0, 0);
  }

#pragma unroll
  for (int i = 0; i < 4; ++i) {
    int grow = m0 + wm + i * 16 + lquad * 4;
#pragma unroll
    for (int j = 0; j < 4; ++j) {
      int gcol = n0 + wn + j * 16 + lrow;
      if (gcol < N) {
#pragma unroll
        for (int r = 0; r < 4; ++r)
          C[(size_t)(grow + r) * N + gcol] = acc[i][j][r];
      }
    }
  }
}

// ---------------- bf16 NT GEMM 64x128 (more blocks for small grids) -------
// waves 2x2: each wave 32 rows x 64 cols. Requires M%64==0, N%128==0.
__global__ __launch_bounds__(256) void gemm_nt_bf16_64(
    const unsigned short* __restrict__ A, const unsigned short* __restrict__ B,
    float* __restrict__ C, int M, int N, int K)
{
  __shared__ unsigned short As[64 * 32];
  __shared__ unsigned short Bs[128 * 32];
  const int m0 = blockIdx.x * 64;
  const int n0 = blockIdx.y * 128;
  const int tid = threadIdx.x;
  const int wave = tid >> 6, lane = tid & 63;
  const int wm = (wave & 1) * 32, wn = (wave >> 1) * 64;
  const int lrow = lane & 15, lquad = lane >> 4;

  v4f acc[2][4] = {};

  for (int k0 = 0; k0 < K; k0 += 32) {
    __syncthreads();
    {
      int e = wave * 64 + lane;             // 0..255 -> A (64 rows)
      int row = e >> 2;
      int kq = (e & 3) * 8;
      const unsigned short* ap = A + (size_t)(m0 + row) * K + k0 + kq;
      // wave writes 64 lanes x 16B = 512 shorts: base = As + wave*512
      GLOAD_LDS16(ap, As + wave * 512);
    }
#pragma unroll
    for (int r = 0; r < 2; ++r) {
      int e = wave * 128 + r * 64 + lane;   // 0..511 -> B (128 rows)
      int row = e >> 2;
      int kq = (e & 3) * 8;
      const unsigned short* bp = B + (size_t)(n0 + row) * K + k0 + kq;
      GLOAD_LDS16(bp, Bs + wave * 1024 + r * 512);
    }
    __syncthreads();
    v8s af[2], bfr[4];
#pragma unroll
    for (int i = 0; i < 2; ++i)
      af[i] = *(const v8s*)&As[(wm + i * 16 + lrow) * 32 + lquad * 8];
#pragma unroll
    for (int j = 0; j < 4; ++j)
      bfr[j] = *(const v8s*)&Bs[(wn + j * 16 + lrow) * 32 + lquad * 8];
#pragma unroll
    for (int i = 0; i < 2; ++i)
#pragma unroll
      for (int j = 0; j < 4; ++j)
        acc[i][j] = __builtin_amdgcn_mfma_f32_16x16x32_bf16(af[i], bfr[j], acc[i][j], 0, 0, 0);
  }

#pragma unroll
  for (int i = 0; i < 2; ++i) {
    int grow = m0 + wm + i * 16 + lquad * 4;
#pragma unroll
    for (int j = 0; j < 4; ++j) {
      int gcol = n0 + wn + j * 16 + lrow;
#pragma unroll
      for (int r = 0; r < 4; ++r)
        C[(size_t)(grow + r) * N + gcol] = acc[i][j][r];
    }
  }
}

// ---------------- causal depthwise conv1d(4) + SiLU ----------------
__global__ void conv_silu_kernel(const float* __restrict__ zx,
                                 const float* __restrict__ cw,
                                 const float* __restrict__ cb,
                                 float* __restrict__ out)
{
  int e = blockIdx.x * 256 + threadIdx.x;   // over L_SEQ*CONVD
  int l = e / CONVD, c = e % CONVD;
  float acc = cb[c];
#pragma unroll
  for (int j = 0; j < 4; ++j) {
    int ls = l - 3 + j;
    if (ls >= 0) acc += zx[(size_t)ls * DPROJ + DIN + c] * cw[c * 4 + j];
  }
  out[e] = acc / (1.f + __expf(-acc));
}

// ---------------- dt = softplus(raw + bias) ----------------
__global__ void dt_kernel(const float* __restrict__ zx,
                          const float* __restrict__ dtb,
                          float* __restrict__ dt)
{
  int e = blockIdx.x * 256 + threadIdx.x;   // over L_SEQ*NH
  int l = e >> 5, h = e & 31;
  float v = zx[(size_t)l * DPROJ + (DPROJ - NH) + h] + dtb[h];
  dt[e] = (v > 20.f) ? v : log1pf(__expf(v));
}

// ---------------- per-(head,chunk) inclusive cumsum of A*dt ----------------
__global__ void acum_kernel(const float* __restrict__ dt,
                            const float* __restrict__ alog,
                            float* __restrict__ acum)
{
  int h = blockIdx.x & 31, c = blockIdx.x >> 5;
  int t = threadIdx.x;
  int l = c * CKLEN + t;
  float A = -__expf(alog[h]);
  __shared__ float s[256];
  s[t] = A * dt[l * NH + h];
  __syncthreads();
  for (int off = 1; off < 256; off <<= 1) {
    float add = (t >= off) ? s[t - off] : 0.f;
    __syncthreads();
    s[t] += add;
    __syncthreads();
  }
  acum[h * L_SEQ + l] = s[t];
}

// ---------------- G[c][l][s] = C_l . B_s (per chunk) ----------------
__global__ __launch_bounds__(256) void g_kernel(const float* __restrict__ xbc,
                                                float* __restrict__ G)
{
  int c = blockIdx.z;
  int l0 = blockIdx.y * 64, s0 = blockIdx.x * 64;
  __shared__ float Cs[64][65];
  __shared__ float Bs[64][65];
  int tid = threadIdx.x;
  for (int e = tid; e < 64 * 64; e += 256) {
    int r = e >> 6, k = e & 63;
    Cs[r][k] = xbc[(size_t)(c * CKLEN + l0 + r) * CONVD + DIN + NSTATE + k];
    Bs[r][k] = xbc[(size_t)(c * CKLEN + s0 + r) * CONVD + DIN + k];
  }
  __syncthreads();
  int tx = tid & 15, ty = tid >> 4;
  float acc[4][4] = {};
  for (int k = 0; k < 64; ++k) {
    float a[4], b[4];
#pragma unroll
    for (int i = 0; i < 4; ++i) a[i] = Cs[ty * 4 + i][k];
#pragma unroll
    for (int j = 0; j < 4; ++j) b[j] = Bs[tx * 4 + j][k];
#pragma unroll
    for (int i = 0; i < 4; ++i)
#pragma unroll
      for (int j = 0; j < 4; ++j) acc[i][j] += a[i] * b[j];
  }
  for (int i = 0; i < 4; ++i)
    for (int j = 0; j < 4; ++j)
      G[((size_t)c * CKLEN + l0 + ty * 4 + i) * CKLEN + s0 + tx * 4 + j] = acc[i][j];
}

// ---------------- chunk states via MFMA: st[c][h][p][n] ----------------
// st[p][n] = sum_t (x[t][p]*dt[t]*decay[t]) * B[t][n]; K = 256.
__global__ __launch_bounds__(256) void states_kernel_mfma(
    const float* __restrict__ xbc, const float* __restrict__ dt,
    const float* __restrict__ acum, float* __restrict__ st)
{
  const int h = blockIdx.x & 31, c = blockIdx.x >> 5;
  const int tid = threadIdx.x;
  const int wave = tid >> 6, lane = tid & 63;
  const int wm = (wave & 1) * 64, wn = (wave >> 1) * 32;
  const int lrow = lane & 15, lquad = lane >> 4;

  __shared__ unsigned short Xt[128 * 32];  // [p][t] slab
  __shared__ unsigned short Bt[64 * 32];   // [n][t] slab
  __shared__ float Wg[256];                // dt * decay per t

  {
    float alast = acum[h * L_SEQ + c * CKLEN + 255];
    int l = c * CKLEN + tid;
    Wg[tid] = dt[l * NH + h] * __expf(fminf(alast - acum[h * L_SEQ + l], 0.f));
  }
  __syncthreads();

  v4f acc[4][2] = {};

  for (int t0 = 0; t0 < CKLEN; t0 += 32) {
    __syncthreads();
#pragma unroll
    for (int i = 0; i < 16; ++i) {
      int e = i * 256 + tid;
      int p = e >> 5, tt = e & 31;
      int l = c * CKLEN + t0 + tt;
      Xt[p * 32 + tt] = to_bf16(xbc[(size_t)l * CONVD + h * HD + p] * Wg[t0 + tt]);
    }
#pragma unroll
    for (int i = 0; i < 8; ++i) {
      int e = i * 256 + tid;
      int n = e >> 5, tt = e & 31;
      int l = c * CKLEN + t0 + tt;
      Bt[n * 32 + tt] = to_bf16(xbc[(size_t)l * CONVD + DIN + n]);
    }
    __syncthreads();
    v8s af[4], bfr[2];
#pragma unroll
    for (int i = 0; i < 4; ++i)
      af[i] = *(const v8s*)&Xt[(wm + i * 16 + lrow) * 32 + lquad * 8];
#pragma unroll
    for (int j = 0; j < 2; ++j)
      bfr[j] = *(const v8s*)&Bt[(wn + j * 16 + lrow) * 32 + lquad * 8];
#pragma unroll
    for (int i = 0; i < 4; ++i)
#pragma unroll
      for (int j = 0; j < 2; ++j)
        acc[i][j] = __builtin_amdgcn_mfma_f32_16x16x32_bf16(af[i], bfr[j], acc[i][j], 0, 0, 0);
  }

  float* outp = st + ((size_t)c * NH + h) * (HD * NSTATE);
#pragma unroll
  for (int i = 0; i < 4; ++i) {
    int p0 = wm + i * 16 + lquad * 4;
#pragma unroll
    for (int j = 0; j < 2; ++j) {
      int n = wn + j * 16 + lrow;
#pragma unroll
      for (int r = 0; r < 4; ++r)
        outp[(size_t)(p0 + r) * NSTATE + n] = acc[i][j][r];
    }
  }
}

// ---------------- inter-chunk scan: sp[c] = states entering chunk c ---------
__global__ void scan_kernel(const float* __restrict__ acum,
                            const float* __restrict__ st,
                            float* __restrict__ sp)
{
  int e = blockIdx.x * 256 + threadIdx.x;   // over NH*HD*NSTATE = 262144
  int h = e >> 13;
  float running = 0.f;
#pragma unroll
  for (int c = 0; c < NCHUNK; ++c) {
    sp[(size_t)c * 262144 + e] = running;
    float dec = __expf(fminf(acum[h * L_SEQ + c * CKLEN + 255], 0.f));
    running = running * dec + st[(size_t)c * 262144 + e];
  }
}

// ---------------- Y = Mexp @ X + (C*eAl) @ S^T + D*xs  (MFMA bf16) --------
__global__ __launch_bounds__(256) void y_kernel_mfma(
    const float* __restrict__ xbc, const float* __restrict__ dt,
    const float* __restrict__ acum, const float* __restrict__ G,
    const float* __restrict__ sp, const float* __restrict__ Dp,
    float* __restrict__ Y)
{
  const int h = blockIdx.x & 31, c = blockIdx.x >> 5;
  const int tid = threadIdx.x;
  const int wave = tid >> 6, lane = tid & 63;
  const int wm = wave * 64;
  const int lrow = lane & 15, lquad = lane >> 4;

  __shared__ unsigned short Ms[256 * 32];
  __shared__ unsigned short Xt[128 * 32];
  __shared__ float Ac[256];

  for (int e = tid; e < 256; e += 256)
    Ac[e] = acum[h * L_SEQ + c * CKLEN + e];

  v4f acc[4][8] = {};

  const float* Gc = G + (size_t)c * (CKLEN * CKLEN);

  for (int k0 = 0; k0 < CKLEN; k0 += 32) {
    __syncthreads();
#pragma unroll
    for (int i = 0; i < 32; ++i) {
      int e = i * 256 + tid;
      int l = e >> 5, sl = e & 31;
      int s = k0 + sl;
      float m = 0.f;
      if (s <= l) m = Gc[l * CKLEN + s] * __expf(fminf(Ac[l] - Ac[s], 0.f));
      Ms[e] = to_bf16(m);
    }
#pragma unroll
    for (int i = 0; i < 16; ++i) {
      int e = i * 256 + tid;
      int ss = e >> 7, p = e & 127;
      int lsg = c * CKLEN + k0 + ss;
      float xv = xbc[(size_t)lsg * CONVD + h * HD + p] * dt[lsg * NH + h];
      Xt[p * 32 + ss] = to_bf16(xv);
    }
    __syncthreads();
    if (k0 < wm + 64) {
      v8s af[4], bfr[8];
#pragma unroll
      for (int i = 0; i < 4; ++i)
        af[i] = *(const v8s*)&Ms[(wm + i * 16 + lrow) * 32 + lquad * 8];
#pragma unroll
      for (int j = 0; j < 8; ++j)
        bfr[j] = *(const v8s*)&Xt[(j * 16 + lrow) * 32 + lquad * 8];
#pragma unroll
      for (int i = 0; i < 4; ++i)
#pragma unroll
        for (int j = 0; j < 8; ++j)
          acc[i][j] = __builtin_amdgcn_mfma_f32_16x16x32_bf16(af[i], bfr[j], acc[i][j], 0, 0, 0);
    }
  }

  const float* Sph = sp + ((size_t)c * NH + h) * (HD * NSTATE);
  for (int n0 = 0; n0 < NSTATE; n0 += 32) {
    __syncthreads();
#pragma unroll
    for (int i = 0; i < 32; ++i) {
      int e = i * 256 + tid;
      int l = e >> 5, nn = e & 31;
      float cv = xbc[(size_t)(c * CKLEN + l) * CONVD + DIN + NSTATE + n0 + nn]
               * __expf(fminf(Ac[l], 0.f));
      Ms[e] = to_bf16(cv);
    }
#pragma unroll
    for (int i = 0; i < 16; ++i) {
      int e = i * 256 + tid;
      int p = e >> 5, nn = e & 31;
      Xt[p * 32 + nn] = to_bf16(Sph[(size_t)p * NSTATE + n0 + nn]);
    }
    __syncthreads();
    v8s af[4], bfr[8];
#pragma unroll
    for (int i = 0; i < 4; ++i)
      af[i] = *(const v8s*)&Ms[(wm + i * 16 + lrow) * 32 + lquad * 8];
#pragma unroll
    for (int j = 0; j < 8; ++j)
      bfr[j] = *(const v8s*)&Xt[(j * 16 + lrow) * 32 + lquad * 8];
#pragma unroll
    for (int i = 0; i < 4; ++i)
#pragma unroll
      for (int j = 0; j < 8; ++j)
        acc[i][j] = __builtin_amdgcn_mfma_f32_16x16x32_bf16(af[i], bfr[j], acc[i][j], 0, 0, 0);
  }

  const float Dh = Dp[h];
#pragma unroll
  for (int i = 0; i < 4; ++i) {
    int rbase = wm + i * 16 + lquad * 4;
#pragma unroll
    for (int j = 0; j < 8; ++j) {
      int p = j * 16 + lrow;
#pragma unroll
      for (int r = 0; r < 4; ++r) {
        int Lg = c * CKLEN + rbase + r;
        float xs = xbc[(size_t)Lg * CONVD + h * HD + p];
        Y[(size_t)Lg * DIN + h * HD + p] = acc[i][j][r] + Dh * xs;
      }
    }
  }
}

// ---------------- gated RMSNorm -> bf16 ----------------
__global__ __launch_bounds__(256) void norm_gate_kernel(const float* __restrict__ Y,
                                                        const float* __restrict__ zx,
                                                        const float* __restrict__ nw,
                                                        unsigned short* __restrict__ gbf)
{
  int l = blockIdx.x;
  int t = threadIdx.x;
  float g[16];
  float ss = 0.f;
#pragma unroll
  for (int i = 0; i < 16; ++i) {
    int idx = i * 256 + t;
    float z = zx[(size_t)l * DPROJ + idx];
    float y = Y[(size_t)l * DIN + idx];
    float gv = y * (z / (1.f + __expf(-z)));
    g[i] = gv;
    ss += gv * gv;
  }
#pragma unroll
  for (int off = 32; off > 0; off >>= 1) ss += __shfl_down(ss, off);
  __shared__ float red[4];
  if ((t & 63) == 0) red[t >> 6] = ss;
  __syncthreads();
  float total = red[0] + red[1] + red[2] + red[3];
  float scale = rsqrtf(total / (float)DIN + 1e-5f);
#pragma unroll
  for (int i = 0; i < 16; ++i) {
    int idx = i * 256 + t;
    gbf[(size_t)l * DIN + idx] = to_bf16(g[i] * scale * nw[idx]);
  }
}

// ---------------- launch ----------------
extern "C" void kernel_launch(void* const* d_in, const int* in_sizes, int n_in,
                              void* d_out, int out_size, void* d_ws, size_t ws_size,
                              hipStream_t stream) {
  const float* x    = (const float*)d_in[0];
  const float* w1   = (const float*)d_in[1];
  const float* cw   = (const float*)d_in[2];
  const float* cb   = (const float*)d_in[3];
  const float* dtb  = (const float*)d_in[4];
  const float* alog = (const float*)d_in[5];
  const float* Dp   = (const float*)d_in[6];
  const float* nw   = (const float*)d_in[7];
  const float* w2   = (const float*)d_in[8];
  float* out = (float*)d_out;
  float* ws  = (float*)d_ws;

  // scratch layout (float units)
  unsigned short* xbf  = (unsigned short*)(ws + 0);          // 2048*2048 bf16
  unsigned short* w1bf = (unsigned short*)(ws + 2097152);    // 8352*2048 bf16
  unsigned short* w2bf = (unsigned short*)(ws + 10649600);   // 2048*4096 bf16
  float* zx   = ws + 14843904;   // 2048*8352
  float* xbc  = ws + 31948800;   // 2048*4224
  float* dt   = ws + 40599552;   // 2048*32
  float* acum = ws + 40665088;   // 32*2048
  float* G    = ws + 40730624;   // 8*256*256
  float* st   = ws + 41254912;   // 8*32*128*64
  float* sp   = ws + 43352064;   // 8*32*128*64
  float* Y    = ws + 45449216;   // 2048*4096
  unsigned short* gbf = (unsigned short*)(ws + 53837824);    // 2048*4096 bf16

  cvt_bf16_kernel<<<4194304 / 2048, 256, 0, stream>>>(x, xbf, 4194304);
  cvt_bf16_kernel<<<17104896 / 2048, 256, 0, stream>>>(w1, w1bf, 17104896);
  cvt_bf16_kernel<<<8388608 / 2048, 256, 0, stream>>>(w2, w2bf, 8388608);

  // zxbcdt = x @ in_proj_w^T   (M=2048, N=8352, K=2048)
  gemm_nt_bf16<<<dim3(16, 66), 256, 0, stream>>>(xbf, w1bf, zx, 2048, 8352, 2048);

  conv_silu_kernel<<<(L_SEQ * CONVD) / 256, 256, 0, stream>>>(zx, cw, cb, xbc);
  dt_kernel<<<(L_SEQ * NH) / 256, 256, 0, stream>>>(zx, dtb, dt);
  acum_kernel<<<NCHUNK * NH, 256, 0, stream>>>(dt, alog, acum);
  g_kernel<<<dim3(4, 4, NCHUNK), 256, 0, stream>>>(xbc, G);
  states_kernel_mfma<<<NCHUNK * NH, 256, 0, stream>>>(xbc, dt, acum, st);
  scan_kernel<<<262144 / 256, 256, 0, stream>>>(acum, st, sp);
  y_kernel_mfma<<<NCHUNK * NH, 256, 0, stream>>>(xbc, dt, acum, G, sp, Dp, Y);
  norm_gate_kernel<<<L_SEQ, 256, 0, stream>>>(Y, zx, nw, gbf);

  // out = g @ out_proj_w^T   (M=2048, N=2048, K=4096) — 64x128 tiles, 512 blocks
  gemm_nt_bf16_64<<<dim3(32, 16), 256, 0, stream>>>(gbf, w2bf, out, 2048, 2048, 4096);
}